// Round 5
// baseline (735.139 us; speedup 1.0000x reference)
//
#include <hip/hip_runtime.h>
#include <math.h>

// Problem constants (match reference)
#define FEAT   128
#define NBANK  1000000
#define KP1    4097            // K_NEG + 1
#define BATCH  256
#define INV_T  2.0f            // 1 / T, T = 0.5
#define EPS_N  1e-7f

// Output layout (floats, concatenated in return order)
constexpr size_t TOTP   = (size_t)BATCH * KP1;        // 1048832 per score output
constexpr size_t O_OUTL = 0;
constexpr size_t O_OUTA = TOTP;                       // 1048832
constexpr size_t O_MEML = 2 * TOTP;                   // 2097664
constexpr size_t O_MEMA = O_MEML + (size_t)NBANK * FEAT; // 130097664

// Scoring tiling: 64 k per block, 16 per wave (16 lanes per 512B row)
constexpr int KCHUNK = 64;
constexpr int NCHUNK = (KP1 + KCHUNK - 1) / KCHUNK;   // 65
constexpr int NPART  = BATCH * NCHUNK;                // 16640 partial-sum slots
constexpr int SCOREB = BATCH * NCHUNK;                // 16640 blocks

// Copy strip-mining folded into the score loop: 8 slots x (bid*256+tid) stride
constexpr size_t N4      = (size_t)NBANK * FEAT / 4;  // 32M float4 per bank
constexpr size_t CSTRIDE = (size_t)SCOREB * 256;      // 4259840

// Workspace layout (floats)
constexpr size_t WS_LN    = 0;
constexpr size_t WS_ABN   = WS_LN + (size_t)BATCH * FEAT;   // 32768
constexpr size_t WS_PARTL = WS_ABN + (size_t)BATCH * FEAT;  // 65536
constexpr size_t WS_PARTA = WS_PARTL + NPART;               // 82176
constexpr size_t WS_INVZ  = WS_PARTA + NPART;               // 98816 (+2)

// Native clang vector type — required for __builtin_nontemporal_*
typedef float vfloat4 __attribute__((ext_vector_type(4)));

__device__ __forceinline__ vfloat4 nt_load4(const vfloat4* p) {
    return __builtin_nontemporal_load(p);
}
__device__ __forceinline__ void nt_store4(vfloat4* p, vfloat4 v) {
    __builtin_nontemporal_store(v, p);
}
__device__ __forceinline__ float dot4(vfloat4 a, vfloat4 b) {
    return a.x * b.x + a.y * b.y + a.z * b.z + a.w * b.w;
}

// ---------------------------------------------------------------------------
// 1) L2-normalize l and ab rows:  x / (sqrt(sum x^2) + eps)
// ---------------------------------------------------------------------------
__global__ void norm_kernel(const float* __restrict__ l,
                            const float* __restrict__ ab,
                            float* __restrict__ ws) {
    int b    = blockIdx.x;
    int lane = threadIdx.x;           // 0..63, 2 floats per lane
    const float* src;
    float*       dst;
    if (b < BATCH) { src = l  + (size_t)b * FEAT;            dst = ws + WS_LN  + (size_t)b * FEAT; }
    else           { src = ab + (size_t)(b - BATCH) * FEAT;  dst = ws + WS_ABN + (size_t)(b - BATCH) * FEAT; }
    float2 v = *(const float2*)(src + 2 * lane);
    float  ss = v.x * v.x + v.y * v.y;
    #pragma unroll
    for (int m = 1; m < 64; m <<= 1) ss += __shfl_xor(ss, m, 64);
    float inv = 1.0f / (sqrtf(ss) + EPS_N);
    ((float2*)dst)[lane] = make_float2(v.x * inv, v.y * inv);
}

// ---------------------------------------------------------------------------
// 2) FUSED score + bank-copy kernel, deep-pipelined.
//    Per wave: 16 k's split into 2 phases of 8 rows-in-flight per bank.
//    Phase order: copy-loads -> gather-loads -> copy-stores -> reduce, so the
//    in-order vmcnt wait for the copy stores does NOT drain the gathers.
//    __launch_bounds__(256,4): ~128 VGPR budget -> loads actually stay in
//    flight (R4's 28-VGPR build serialized every phase).
// ---------------------------------------------------------------------------
__global__ __launch_bounds__(256, 4) void fused_kernel(
        const float* __restrict__ mem_l, const float* __restrict__ mem_ab,
        const int*   __restrict__ idx,
        const float* __restrict__ ws_in,   // ln/abn
        float* __restrict__ out,
        float* __restrict__ part_l, float* __restrict__ part_ab) {
    int sid    = blockIdx.x;                 // 0..SCOREB-1
    int b      = sid % BATCH;
    int chunk  = sid / BATCH;                // 0..NCHUNK-1
    int wave   = threadIdx.x >> 6;
    int lane   = threadIdx.x & 63;
    int lane16 = lane & 15;                  // position within row (x8 floats)
    int g      = lane >> 4;                  // group = which k of a 4-batch

    // query fragments for this lane's 32B row segment
    const vfloat4* lnp = (const vfloat4*)(ws_in + WS_LN  + (size_t)b * FEAT);
    const vfloat4* abp = (const vfloat4*)(ws_in + WS_ABN + (size_t)b * FEAT);
    vfloat4 lv0 = lnp[lane16 * 2], lv1 = lnp[lane16 * 2 + 1];
    vfloat4 av0 = abp[lane16 * 2], av1 = abp[lane16 * 2 + 1];

    // copy pointers
    const vfloat4* ca = (const vfloat4*)mem_l;
    const vfloat4* cb = (const vfloat4*)mem_ab;
    vfloat4* ol = (vfloat4*)(out + O_MEML);
    vfloat4* oa = (vfloat4*)(out + O_MEMA);
    size_t cbase = (size_t)sid * 256 + threadIdx.x;

    const int* idx_b = idx + (size_t)b * KP1;
    int kw = chunk * KCHUNK + wave * 16;     // wave's first k

    // preload the wave's 4 row indices per lane (t = 0..3 -> k = kw + 4t + g)
    int kk[4], rows[4];
    #pragma unroll
    for (int t = 0; t < 4; ++t) {
        kk[t] = kw + 4 * t + g;
        rows[t] = (kk[t] < KP1) ? idx_b[kk[t]] : 0;
    }

    float sum_l = 0.f, sum_ab = 0.f;
    #pragma unroll
    for (int p = 0; p < 2; ++p) {
        // ---- copy loads (4 slots x 2 banks), non-temporal ----
        vfloat4 cl[4], cab[4];
        size_t ci[4];
        #pragma unroll
        for (int j = 0; j < 4; ++j) {
            ci[j] = cbase + (size_t)(4 * p + j) * CSTRIDE;
            if (ci[j] < N4) { cl[j] = nt_load4(ca + ci[j]); cab[j] = nt_load4(cb + ci[j]); }
        }
        // ---- gather loads: 2 k's per lane (t = 2p, 2p+1), both banks ----
        int r0 = rows[2 * p], r1 = rows[2 * p + 1];
        const vfloat4* pa0 = (const vfloat4*)(mem_ab + (size_t)r0 * FEAT) + lane16 * 2;
        const vfloat4* pw0 = (const vfloat4*)(mem_l  + (size_t)r0 * FEAT) + lane16 * 2;
        const vfloat4* pa1 = (const vfloat4*)(mem_ab + (size_t)r1 * FEAT) + lane16 * 2;
        const vfloat4* pw1 = (const vfloat4*)(mem_l  + (size_t)r1 * FEAT) + lane16 * 2;
        vfloat4 a00 = pa0[0], a01 = pa0[1];
        vfloat4 w00 = pw0[0], w01 = pw0[1];
        vfloat4 a10 = pa1[0], a11 = pa1[1];
        vfloat4 w10 = pw1[0], w11 = pw1[1];
        // ---- copy stores (wait only on copy loads; gathers stay in flight) ----
        #pragma unroll
        for (int j = 0; j < 4; ++j) {
            if (ci[j] < N4) { nt_store4(ol + ci[j], cl[j]); nt_store4(oa + ci[j], cab[j]); }
        }
        // ---- reduce both k's ----
        float dl0  = dot4(a00, lv0) + dot4(a01, lv1);
        float dab0 = dot4(w00, av0) + dot4(w01, av1);
        float dl1  = dot4(a10, lv0) + dot4(a11, lv1);
        float dab1 = dot4(w10, av0) + dot4(w11, av1);
        #pragma unroll
        for (int m = 1; m < 16; m <<= 1) {
            dl0  += __shfl_xor(dl0,  m, 64);
            dab0 += __shfl_xor(dab0, m, 64);
            dl1  += __shfl_xor(dl1,  m, 64);
            dab1 += __shfl_xor(dab1, m, 64);
        }
        bool v0 = kk[2 * p] < KP1, v1 = kk[2 * p + 1] < KP1;
        float pl0  = v0 ? __expf(dl0  * INV_T) : 0.f;
        float pab0 = v0 ? __expf(dab0 * INV_T) : 0.f;
        float pl1  = v1 ? __expf(dl1  * INV_T) : 0.f;
        float pab1 = v1 ? __expf(dab1 * INV_T) : 0.f;
        if (lane16 == 0) {
            if (v0) {
                out[O_OUTL + (size_t)b * KP1 + kk[2 * p]] = pl0;
                out[O_OUTA + (size_t)b * KP1 + kk[2 * p]] = pab0;
            }
            if (v1) {
                out[O_OUTL + (size_t)b * KP1 + kk[2 * p + 1]] = pl1;
                out[O_OUTA + (size_t)b * KP1 + kk[2 * p + 1]] = pab1;
            }
        }
        sum_l += pl0 + pl1; sum_ab += pab0 + pab1;   // same within 16-group
    }
    // cross-group reduce (4 groups -> wave total on every lane)
    #pragma unroll
    for (int m = 16; m < 64; m <<= 1) {
        sum_l  += __shfl_xor(sum_l,  m, 64);
        sum_ab += __shfl_xor(sum_ab, m, 64);
    }
    __shared__ float s[8];
    if (lane == 0) { s[wave] = sum_l; s[4 + wave] = sum_ab; }
    __syncthreads();
    if (threadIdx.x == 0) {
        part_l[(size_t)b * NCHUNK + chunk]  = s[0] + s[1] + s[2] + s[3];
        part_ab[(size_t)b * NCHUNK + chunk] = s[4] + s[5] + s[6] + s[7];
    }
}

// ---------------------------------------------------------------------------
// 3) Deterministic reduction of partials -> 1/Z for both outputs
// ---------------------------------------------------------------------------
__global__ void zreduce_kernel(const float* __restrict__ part_l,
                               const float* __restrict__ part_ab,
                               float* __restrict__ invz) {
    __shared__ float sl[256], sa[256];
    float a = 0.f, b = 0.f;
    for (int i = threadIdx.x; i < NPART; i += 256) { a += part_l[i]; b += part_ab[i]; }
    sl[threadIdx.x] = a; sa[threadIdx.x] = b;
    __syncthreads();
    for (int s = 128; s > 0; s >>= 1) {
        if (threadIdx.x < (unsigned)s) {
            sl[threadIdx.x] += sl[threadIdx.x + s];
            sa[threadIdx.x] += sa[threadIdx.x + s];
        }
        __syncthreads();
    }
    if (threadIdx.x == 0) {
        float count = (float)TOTP;
        // out = P / Z, Z = (sum/count) * NBANK  ->  invZ = count / (sum * NBANK)
        invz[0] = count / (sl[0] * (float)NBANK);
        invz[1] = count / (sa[0] * (float)NBANK);
    }
}

// ---------------------------------------------------------------------------
// 4) Scale both P regions in place by 1/Z
// ---------------------------------------------------------------------------
__global__ void scale_kernel(float* __restrict__ out, const float* __restrict__ invz) {
    float zl = invz[0], za = invz[1];
    size_t stride = (size_t)gridDim.x * blockDim.x;
    for (size_t i = (size_t)blockIdx.x * blockDim.x + threadIdx.x; i < TOTP; i += stride) {
        out[O_OUTL + i] *= zl;
        out[O_OUTA + i] *= za;
    }
}

// ---------------------------------------------------------------------------
// 5) Momentum scatter update (reads ORIGINAL banks, writes into d_out copies)
//    Last-wins on duplicate y to match numpy scatter semantics.
// ---------------------------------------------------------------------------
__global__ void update_kernel(const float* __restrict__ mem_l,
                              const float* __restrict__ mem_ab,
                              const int*   __restrict__ y,
                              const float* __restrict__ ws,
                              float* __restrict__ out) {
    int b    = blockIdx.x;
    int lane = threadIdx.x;
    int row  = y[b];
    for (int j = b + 1; j < BATCH; ++j)
        if (y[j] == row) return;              // a later write wins
    // --- bank L ---
    {
        float2 m = ((const float2*)(mem_l + (size_t)row * FEAT))[lane];
        float2 x = ((const float2*)(ws + WS_LN + (size_t)b * FEAT))[lane];
        float2 p = make_float2(m.x * 0.5f + x.x * 0.5f, m.y * 0.5f + x.y * 0.5f);
        float ss = p.x * p.x + p.y * p.y;
        #pragma unroll
        for (int mk = 1; mk < 64; mk <<= 1) ss += __shfl_xor(ss, mk, 64);
        float nrm = sqrtf(ss);
        ((float2*)(out + O_MEML + (size_t)row * FEAT))[lane] =
            make_float2(p.x / nrm, p.y / nrm);
    }
    // --- bank AB ---
    {
        float2 m = ((const float2*)(mem_ab + (size_t)row * FEAT))[lane];
        float2 x = ((const float2*)(ws + WS_ABN + (size_t)b * FEAT))[lane];
        float2 p = make_float2(m.x * 0.5f + x.x * 0.5f, m.y * 0.5f + x.y * 0.5f);
        float ss = p.x * p.x + p.y * p.y;
        #pragma unroll
        for (int mk = 1; mk < 64; mk <<= 1) ss += __shfl_xor(ss, mk, 64);
        float nrm = sqrtf(ss);
        ((float2*)(out + O_MEMA + (size_t)row * FEAT))[lane] =
            make_float2(p.x / nrm, p.y / nrm);
    }
}

// ---------------------------------------------------------------------------
extern "C" void kernel_launch(void* const* d_in, const int* in_sizes, int n_in,
                              void* d_out, int out_size, void* d_ws, size_t ws_size,
                              hipStream_t stream) {
    const float* l      = (const float*)d_in[0];
    const float* ab     = (const float*)d_in[1];
    const float* mem_l  = (const float*)d_in[2];
    const float* mem_ab = (const float*)d_in[3];
    const int*   y      = (const int*)d_in[4];
    const int*   idx    = (const int*)d_in[5];
    float* out = (float*)d_out;
    float* ws  = (float*)d_ws;

    // 1) normalize
    norm_kernel<<<dim3(2 * BATCH), dim3(64), 0, stream>>>(l, ab, ws);
    // 2) fused score + bank copy (deep-pipelined uniform blocks)
    fused_kernel<<<dim3(SCOREB), dim3(256), 0, stream>>>(
        mem_l, mem_ab, idx, ws, out, ws + WS_PARTL, ws + WS_PARTA);
    // 3) Z
    zreduce_kernel<<<dim3(1), dim3(256), 0, stream>>>(ws + WS_PARTL, ws + WS_PARTA, ws + WS_INVZ);
    // 4) scale
    scale_kernel<<<dim3(1024), dim3(256), 0, stream>>>(out, ws + WS_INVZ);
    // 5) momentum scatter (after copy, last-wins)
    update_kernel<<<dim3(BATCH), dim3(64), 0, stream>>>(mem_l, mem_ab, y, ws, out);
}

// Round 6
// 577.505 us; speedup vs baseline: 1.2730x; 1.2730x over previous
//
#include <hip/hip_runtime.h>
#include <math.h>
#include <stdint.h>

// Problem constants (match reference)
#define FEAT   128
#define NBANK  1000000
#define KP1    4097            // K_NEG + 1
#define BATCH  256
#define INV_T  2.0f            // 1 / T, T = 0.5
#define EPS_N  1e-7f

// Output layout (floats, concatenated in return order)
constexpr size_t TOTP   = (size_t)BATCH * KP1;        // 1048832 per score output
constexpr size_t O_OUTL = 0;
constexpr size_t O_OUTA = TOTP;                       // 1048832
constexpr size_t O_MEML = 2 * TOTP;                   // 2097664
constexpr size_t O_MEMA = O_MEML + (size_t)NBANK * FEAT; // 130097664

// Inverted-index geometry: buckets of 32 bank rows
constexpr int RPB   = 32;
constexpr int NBUCK = NBANK / RPB;                    // 31250 (exact)

// Workspace layout. Float region first, then u32 region.
constexpr size_t WS_LN   = 0;        // 256*128 floats
constexpr size_t WS_ABN  = 32768;    // 256*128 floats
constexpr size_t WS_INVZ = 65536;    // 2 floats
constexpr size_t WS_PL   = 65544;    // 256 floats (Z partials, out_l)
constexpr size_t WS_PA   = 65800;    // 256 floats (Z partials, out_ab)
constexpr size_t WS_U32  = 66560;    // u32 region starts here (float index)
// u32 region (offsets in u32 units from ws_u base):
//   CNT   [NBUCK]      bucket counts
//   START [NBUCK]      bucket start offsets (immutable)
//   CUR   [NBUCK]      bucket cursors (end offsets after scatter)
//   ENT   [TOTP]       packed entries: (b<<18)|(k<<5)|(row&31)
// total ws ≈ 4.85 MB

typedef float vfloat4 __attribute__((ext_vector_type(4)));

__device__ __forceinline__ void nt_store4(vfloat4* p, vfloat4 v) {
    __builtin_nontemporal_store(v, p);
}
__device__ __forceinline__ float dot4(vfloat4 a, vfloat4 b) {
    return a.x * b.x + a.y * b.y + a.z * b.z + a.w * b.w;
}

// ---------------------------------------------------------------------------
// 1) L2-normalize l and ab rows:  x / (sqrt(sum x^2) + eps)
// ---------------------------------------------------------------------------
__global__ void norm_kernel(const float* __restrict__ l,
                            const float* __restrict__ ab,
                            float* __restrict__ ws) {
    int b    = blockIdx.x;
    int lane = threadIdx.x;           // 0..63, 2 floats per lane
    const float* src;
    float*       dst;
    if (b < BATCH) { src = l  + (size_t)b * FEAT;            dst = ws + WS_LN  + (size_t)b * FEAT; }
    else           { src = ab + (size_t)(b - BATCH) * FEAT;  dst = ws + WS_ABN + (size_t)(b - BATCH) * FEAT; }
    float2 v = *(const float2*)(src + 2 * lane);
    float  ss = v.x * v.x + v.y * v.y;
    #pragma unroll
    for (int m = 1; m < 64; m <<= 1) ss += __shfl_xor(ss, m, 64);
    float inv = 1.0f / (sqrtf(ss) + EPS_N);
    ((float2*)dst)[lane] = make_float2(v.x * inv, v.y * inv);
}

// ---------------------------------------------------------------------------
// 2a) zero bucket counts
// ---------------------------------------------------------------------------
__global__ void zero_kernel(unsigned int* __restrict__ cnt) {
    int stride = gridDim.x * blockDim.x;
    for (int i = blockIdx.x * blockDim.x + threadIdx.x; i < NBUCK; i += stride)
        cnt[i] = 0u;
}

// ---------------------------------------------------------------------------
// 2b) histogram idx entries into row-buckets
// ---------------------------------------------------------------------------
__global__ void hist_kernel(const int* __restrict__ idx,
                            unsigned int* __restrict__ cnt) {
    int stride = gridDim.x * blockDim.x;
    for (size_t p = (size_t)blockIdx.x * blockDim.x + threadIdx.x; p < TOTP; p += stride) {
        int row = idx[p];
        atomicAdd(&cnt[row >> 5], 1u);
    }
}

// ---------------------------------------------------------------------------
// 2c) exclusive scan over NBUCK counts (single block; integer => deterministic)
// ---------------------------------------------------------------------------
__global__ void scan_kernel(const unsigned int* __restrict__ cnt,
                            unsigned int* __restrict__ start,
                            unsigned int* __restrict__ cur) {
    __shared__ unsigned int ts[256];
    __shared__ unsigned int ex[256];
    int t = threadIdx.x;
    const int Q = (NBUCK + 255) / 256;            // 123
    int lo = t * Q, hi = lo + Q; if (hi > NBUCK) hi = NBUCK;
    unsigned int s = 0;
    for (int i = lo; i < hi; ++i) s += cnt[i];
    ts[t] = s;
    __syncthreads();
    if (t == 0) {
        unsigned int r = 0;
        for (int i = 0; i < 256; ++i) { ex[i] = r; r += ts[i]; }
    }
    __syncthreads();
    unsigned int base = ex[t];
    for (int i = lo; i < hi; ++i) {
        start[i] = base; cur[i] = base;
        base += cnt[i];
    }
}

// ---------------------------------------------------------------------------
// 2d) scatter packed entries into buckets (order within bucket is arbitrary;
//     every (b,k) lands in exactly one slot, so P outputs stay deterministic)
// ---------------------------------------------------------------------------
__global__ void scatter_kernel(const int* __restrict__ idx,
                               unsigned int* __restrict__ cur,
                               unsigned int* __restrict__ ent) {
    int stride = gridDim.x * blockDim.x;
    for (size_t p = (size_t)blockIdx.x * blockDim.x + threadIdx.x; p < TOTP; p += stride) {
        int row = idx[p];
        int b   = (int)(p / KP1);
        int k   = (int)(p - (size_t)b * KP1);
        unsigned int pos = atomicAdd(&cur[row >> 5], 1u);
        ent[pos] = ((unsigned int)b << 18) | ((unsigned int)k << 5) | (unsigned int)(row & 31);
    }
}

// ---------------------------------------------------------------------------
// 3) MAIN: stream 32-row window of both banks (copy out, stage in LDS),
//    then score this window's entries from LDS. HBM sees pure streaming.
// ---------------------------------------------------------------------------
__global__ __launch_bounds__(256) void main_kernel(
        const float* __restrict__ mem_l, const float* __restrict__ mem_ab,
        const float* __restrict__ ws_f,            // ln/abn tables
        const unsigned int* __restrict__ start,
        const unsigned int* __restrict__ cur,
        const unsigned int* __restrict__ ent,
        float* __restrict__ out) {
    __shared__ float ldsL[RPB * FEAT];   // 16 KB
    __shared__ float ldsA[RPB * FEAT];   // 16 KB
    int blk = blockIdx.x;                // 0..NBUCK-1
    int tid = threadIdx.x;
    size_t fbase = (size_t)blk * RPB * FEAT;       // float offset of window

    // ---- stage + copy: 1024 float4 per bank, 4 per thread ----
    const vfloat4* sl = (const vfloat4*)(mem_l  + fbase);
    const vfloat4* sa = (const vfloat4*)(mem_ab + fbase);
    vfloat4* dl_ = (vfloat4*)(out + O_MEML + fbase);
    vfloat4* da_ = (vfloat4*)(out + O_MEMA + fbase);
    vfloat4* lL = (vfloat4*)ldsL;
    vfloat4* lA = (vfloat4*)ldsA;
    vfloat4 vl[4], va[4];
    #pragma unroll
    for (int j = 0; j < 4; ++j) { vl[j] = sl[j * 256 + tid]; }
    #pragma unroll
    for (int j = 0; j < 4; ++j) { va[j] = sa[j * 256 + tid]; }
    #pragma unroll
    for (int j = 0; j < 4; ++j) {
        int i = j * 256 + tid;
        lL[i] = vl[j]; nt_store4(dl_ + i, vl[j]);
        lA[i] = va[j]; nt_store4(da_ + i, va[j]);
    }
    __syncthreads();

    // ---- score this window's entries from LDS ----
    int s = (int)start[blk], e = (int)cur[blk];
    int g = tid >> 4, lane16 = tid & 15;           // 16 groups of 16 lanes
    for (int i = s + g; i < e; i += 16) {
        unsigned int ev = ent[i];
        int rloc = (int)(ev & 31u);
        int k    = (int)((ev >> 5) & 0x1FFFu);
        int b    = (int)(ev >> 18);
        const vfloat4* ra = (const vfloat4*)(ldsA + rloc * FEAT) + lane16 * 2;
        const vfloat4* rl = (const vfloat4*)(ldsL + rloc * FEAT) + lane16 * 2;
        vfloat4 wa0 = ra[0], wa1 = ra[1];          // memory_ab row
        vfloat4 wl0 = rl[0], wl1 = rl[1];          // memory_l  row
        const vfloat4* lq = (const vfloat4*)(ws_f + WS_LN  + (size_t)b * FEAT) + lane16 * 2;
        const vfloat4* aq = (const vfloat4*)(ws_f + WS_ABN + (size_t)b * FEAT) + lane16 * 2;
        vfloat4 lv0 = lq[0], lv1 = lq[1];
        vfloat4 av0 = aq[0], av1 = aq[1];
        float dl  = dot4(wa0, lv0) + dot4(wa1, lv1);   // -> P_l
        float dab = dot4(wl0, av0) + dot4(wl1, av1);   // -> P_ab
        #pragma unroll
        for (int m = 1; m < 16; m <<= 1) {
            dl  += __shfl_xor(dl,  m, 64);
            dab += __shfl_xor(dab, m, 64);
        }
        if (lane16 == 0) {
            out[O_OUTL + (size_t)b * KP1 + k] = __expf(dl  * INV_T);
            out[O_OUTA + (size_t)b * KP1 + k] = __expf(dab * INV_T);
        }
    }
}

// ---------------------------------------------------------------------------
// 4a) Z partials from the completed P arrays, fixed slicing (deterministic)
//     256 blocks: block i owns batch-row i (4097 elements of each array)
// ---------------------------------------------------------------------------
__global__ void zsum_kernel(const float* __restrict__ out,
                            float* __restrict__ pl, float* __restrict__ pa) {
    __shared__ float sl[256], sa[256];
    int i = blockIdx.x, t = threadIdx.x;
    const float* bl = out + O_OUTL + (size_t)i * KP1;
    const float* ba = out + O_OUTA + (size_t)i * KP1;
    float a = 0.f, b = 0.f;
    for (int p = t; p < KP1; p += 256) { a += bl[p]; b += ba[p]; }
    sl[t] = a; sa[t] = b;
    __syncthreads();
    for (int s = 128; s > 0; s >>= 1) {
        if (t < s) { sl[t] += sl[t + s]; sa[t] += sa[t + s]; }
        __syncthreads();
    }
    if (t == 0) { pl[i] = sl[0]; pa[i] = sa[0]; }
}

// ---------------------------------------------------------------------------
// 4b) final Z -> 1/Z
// ---------------------------------------------------------------------------
__global__ void zfinal_kernel(const float* __restrict__ pl,
                              const float* __restrict__ pa,
                              float* __restrict__ invz) {
    if (threadIdx.x == 0) {
        float a = 0.f, b = 0.f;
        for (int i = 0; i < 256; ++i) { a += pl[i]; b += pa[i]; }
        float count = (float)TOTP;
        invz[0] = count / (a * (float)NBANK);
        invz[1] = count / (b * (float)NBANK);
    }
}

// ---------------------------------------------------------------------------
// 5) Scale both P regions in place by 1/Z
// ---------------------------------------------------------------------------
__global__ void scale_kernel(float* __restrict__ out, const float* __restrict__ invz) {
    float zl = invz[0], za = invz[1];
    size_t stride = (size_t)gridDim.x * blockDim.x;
    for (size_t i = (size_t)blockIdx.x * blockDim.x + threadIdx.x; i < TOTP; i += stride) {
        out[O_OUTL + i] *= zl;
        out[O_OUTA + i] *= za;
    }
}

// ---------------------------------------------------------------------------
// 6) Momentum scatter update (reads ORIGINAL banks, writes into d_out copies)
//    Last-wins on duplicate y to match numpy scatter semantics.
// ---------------------------------------------------------------------------
__global__ void update_kernel(const float* __restrict__ mem_l,
                              const float* __restrict__ mem_ab,
                              const int*   __restrict__ y,
                              const float* __restrict__ ws,
                              float* __restrict__ out) {
    int b    = blockIdx.x;
    int lane = threadIdx.x;
    int row  = y[b];
    for (int j = b + 1; j < BATCH; ++j)
        if (y[j] == row) return;              // a later write wins
    {
        float2 m = ((const float2*)(mem_l + (size_t)row * FEAT))[lane];
        float2 x = ((const float2*)(ws + WS_LN + (size_t)b * FEAT))[lane];
        float2 p = make_float2(m.x * 0.5f + x.x * 0.5f, m.y * 0.5f + x.y * 0.5f);
        float ss = p.x * p.x + p.y * p.y;
        #pragma unroll
        for (int mk = 1; mk < 64; mk <<= 1) ss += __shfl_xor(ss, mk, 64);
        float nrm = sqrtf(ss);
        ((float2*)(out + O_MEML + (size_t)row * FEAT))[lane] =
            make_float2(p.x / nrm, p.y / nrm);
    }
    {
        float2 m = ((const float2*)(mem_ab + (size_t)row * FEAT))[lane];
        float2 x = ((const float2*)(ws + WS_ABN + (size_t)b * FEAT))[lane];
        float2 p = make_float2(m.x * 0.5f + x.x * 0.5f, m.y * 0.5f + x.y * 0.5f);
        float ss = p.x * p.x + p.y * p.y;
        #pragma unroll
        for (int mk = 1; mk < 64; mk <<= 1) ss += __shfl_xor(ss, mk, 64);
        float nrm = sqrtf(ss);
        ((float2*)(out + O_MEMA + (size_t)row * FEAT))[lane] =
            make_float2(p.x / nrm, p.y / nrm);
    }
}

// ---------------------------------------------------------------------------
extern "C" void kernel_launch(void* const* d_in, const int* in_sizes, int n_in,
                              void* d_out, int out_size, void* d_ws, size_t ws_size,
                              hipStream_t stream) {
    const float* l      = (const float*)d_in[0];
    const float* ab     = (const float*)d_in[1];
    const float* mem_l  = (const float*)d_in[2];
    const float* mem_ab = (const float*)d_in[3];
    const int*   y      = (const int*)d_in[4];
    const int*   idx    = (const int*)d_in[5];
    float* out = (float*)d_out;
    float* ws  = (float*)d_ws;

    unsigned int* wsu   = (unsigned int*)(ws + WS_U32);
    unsigned int* cnt   = wsu;
    unsigned int* start = wsu + NBUCK;
    unsigned int* cur   = wsu + 2 * (size_t)NBUCK;
    unsigned int* ent   = wsu + 3 * (size_t)NBUCK;

    // 1) normalize queries
    norm_kernel<<<dim3(2 * BATCH), dim3(64), 0, stream>>>(l, ab, ws);
    // 2) build inverted index (row-bucket -> entries)
    zero_kernel   <<<dim3(128),  dim3(256), 0, stream>>>(cnt);
    hist_kernel   <<<dim3(2048), dim3(256), 0, stream>>>(idx, cnt);
    scan_kernel   <<<dim3(1),    dim3(256), 0, stream>>>(cnt, start, cur);
    scatter_kernel<<<dim3(2048), dim3(256), 0, stream>>>(idx, cur, ent);
    // 3) stream banks: copy out + score from LDS (pure-streaming HBM)
    main_kernel<<<dim3(NBUCK), dim3(256), 0, stream>>>(
        mem_l, mem_ab, ws, start, cur, ent, out);
    // 4) Z from completed P arrays (fixed order)
    zsum_kernel  <<<dim3(256), dim3(256), 0, stream>>>(out, ws + WS_PL, ws + WS_PA);
    zfinal_kernel<<<dim3(1),   dim3(64),  0, stream>>>(ws + WS_PL, ws + WS_PA, ws + WS_INVZ);
    // 5) scale P by 1/Z
    scale_kernel<<<dim3(1024), dim3(256), 0, stream>>>(out, ws + WS_INVZ);
    // 6) momentum scatter update (after copy, last-wins)
    update_kernel<<<dim3(BATCH), dim3(64), 0, stream>>>(mem_l, mem_ab, y, ws, out);
}

// Round 7
// 490.925 us; speedup vs baseline: 1.4975x; 1.1764x over previous
//
#include <hip/hip_runtime.h>
#include <math.h>
#include <stdint.h>

// Problem constants (match reference)
#define FEAT   128
#define NBANK  1000000
#define KP1    4097            // K_NEG + 1
#define BATCH  256
#define INV_T  2.0f            // 1 / T, T = 0.5
#define EPS_N  1e-7f

// Output layout (floats, concatenated in return order)
constexpr size_t TOTP   = (size_t)BATCH * KP1;        // 1048832 per score output
constexpr size_t O_OUTL = 0;
constexpr size_t O_OUTA = TOTP;                       // 1048832
constexpr size_t O_MEML = 2 * TOTP;                   // 2097664
constexpr size_t O_MEMA = O_MEML + (size_t)NBANK * FEAT; // 130097664

// Inverted-index geometry: buckets of 32 bank rows, fixed-capacity slots.
// Avg entries/bucket = 1048832/31250 = 33.6 (Poisson); CAP=192 is ~27 sigma.
constexpr int RPB   = 32;
constexpr int NBUCK = NBANK / RPB;                    // 31250 (exact)
constexpr int CAP   = 192;

// Workspace layout. Float region first, then u32 region.
constexpr size_t WS_LN   = 0;        // 256*128 floats
constexpr size_t WS_ABN  = 32768;    // 256*128 floats
constexpr size_t WS_INVZ = 65536;    // 2 floats
constexpr size_t WS_PL   = 65544;    // 256 floats (Z partials, out_l)
constexpr size_t WS_PA   = 65800;    // 256 floats (Z partials, out_ab)
constexpr size_t WS_U32  = 66560;    // u32 region starts here (float index)
// u32 region: CNT[NBUCK], ENT[NBUCK*CAP]  (~24 MB total)

typedef float vfloat4 __attribute__((ext_vector_type(4)));

__device__ __forceinline__ float dot4(vfloat4 a, vfloat4 b) {
    return a.x * b.x + a.y * b.y + a.z * b.z + a.w * b.w;
}

// ---------------------------------------------------------------------------
// 1) L2-normalize l and ab rows + zero bucket counters (folded).
//    512 blocks x 64 threads; gid in [0,32768) covers NBUCK=31250 counters.
// ---------------------------------------------------------------------------
__global__ void norm_zero_kernel(const float* __restrict__ l,
                                 const float* __restrict__ ab,
                                 float* __restrict__ ws,
                                 unsigned int* __restrict__ cnt) {
    int b    = blockIdx.x;
    int lane = threadIdx.x;           // 0..63, 2 floats per lane
    int gid  = b * 64 + lane;
    if (gid < NBUCK) cnt[gid] = 0u;
    const float* src;
    float*       dst;
    if (b < BATCH) { src = l  + (size_t)b * FEAT;            dst = ws + WS_LN  + (size_t)b * FEAT; }
    else           { src = ab + (size_t)(b - BATCH) * FEAT;  dst = ws + WS_ABN + (size_t)(b - BATCH) * FEAT; }
    float2 v = *(const float2*)(src + 2 * lane);
    float  ss = v.x * v.x + v.y * v.y;
    #pragma unroll
    for (int m = 1; m < 64; m <<= 1) ss += __shfl_xor(ss, m, 64);
    float inv = 1.0f / (sqrtf(ss) + EPS_N);
    ((float2*)dst)[lane] = make_float2(v.x * inv, v.y * inv);
}

// ---------------------------------------------------------------------------
// 2) Build inverted index in ONE pass: fixed-capacity buckets.
//    Entry pack: (b<<18)|(k<<5)|(row&31). Order within bucket is arbitrary
//    (atomic), but every (b,k) gets exactly one slot -> P deterministic.
// ---------------------------------------------------------------------------
__global__ void build_kernel(const int* __restrict__ idx,
                             unsigned int* __restrict__ cnt,
                             unsigned int* __restrict__ ent) {
    size_t stride = (size_t)gridDim.x * blockDim.x;
    for (size_t p = (size_t)blockIdx.x * blockDim.x + threadIdx.x; p < TOTP; p += stride) {
        int row = idx[p];
        int b   = (int)(p / KP1);
        int k   = (int)(p - (size_t)b * KP1);
        int bucket = row >> 5;
        unsigned int pos = atomicAdd(&cnt[bucket], 1u);
        if (pos < (unsigned int)CAP)
            ent[(size_t)bucket * CAP + pos] =
                ((unsigned int)b << 18) | ((unsigned int)k << 5) | (unsigned int)(row & 31);
    }
}

// ---------------------------------------------------------------------------
// 3) MAIN: stream a 32-row window of both banks. Structure per block:
//    global loads (regs) -> LDS writes -> barrier -> PLAIN stores (copy-out,
//    overlapped with score) -> score window entries from LDS.
//    Stores after the barrier so its vmcnt(0) drain doesn't serialize them;
//    plain (not nt) stores: the fill kernel proves 6.8 TB/s on this path.
// ---------------------------------------------------------------------------
__global__ __launch_bounds__(256) void main_kernel(
        const float* __restrict__ mem_l, const float* __restrict__ mem_ab,
        const float* __restrict__ ws_f,            // ln/abn tables
        const unsigned int* __restrict__ cnt,
        const unsigned int* __restrict__ ent,
        float* __restrict__ out) {
    __shared__ float ldsL[RPB * FEAT];   // 16 KB
    __shared__ float ldsA[RPB * FEAT];   // 16 KB
    __shared__ unsigned int sEnt[CAP];   // 768 B
    int blk = blockIdx.x;                // 0..NBUCK-1
    int tid = threadIdx.x;
    size_t fbase = (size_t)blk * RPB * FEAT;       // float offset of window

    // ---- issue global loads: 4 float4 per thread per bank (16 KB each) ----
    const vfloat4* sl = (const vfloat4*)(mem_l  + fbase);
    const vfloat4* sa = (const vfloat4*)(mem_ab + fbase);
    vfloat4 vl[4], va[4];
    #pragma unroll
    for (int j = 0; j < 4; ++j) vl[j] = sl[j * 256 + tid];
    #pragma unroll
    for (int j = 0; j < 4; ++j) va[j] = sa[j * 256 + tid];

    // ---- stage this bucket's entries into LDS ----
    int c = min((int)cnt[blk], CAP);
    for (int i = tid; i < c; i += 256) sEnt[i] = ent[(size_t)blk * CAP + i];

    // ---- LDS writes ----
    vfloat4* lL = (vfloat4*)ldsL;
    vfloat4* lA = (vfloat4*)ldsA;
    #pragma unroll
    for (int j = 0; j < 4; ++j) { int i = j * 256 + tid; lL[i] = vl[j]; lA[i] = va[j]; }
    __syncthreads();

    // ---- copy-out (plain stores, overlap with score below) ----
    vfloat4* dl_ = (vfloat4*)(out + O_MEML + fbase);
    vfloat4* da_ = (vfloat4*)(out + O_MEMA + fbase);
    #pragma unroll
    for (int j = 0; j < 4; ++j) { int i = j * 256 + tid; dl_[i] = vl[j]; da_[i] = va[j]; }

    // ---- score this window's entries from LDS ----
    int g = tid >> 4, lane16 = tid & 15;           // 16 groups of 16 lanes
    for (int i = g; i < c; i += 16) {
        unsigned int ev = sEnt[i];
        int rloc = (int)(ev & 31u);
        int k    = (int)((ev >> 5) & 0x1FFFu);
        int b    = (int)(ev >> 18);
        const vfloat4* ra = (const vfloat4*)(ldsA + rloc * FEAT) + lane16 * 2;
        const vfloat4* rl = (const vfloat4*)(ldsL + rloc * FEAT) + lane16 * 2;
        vfloat4 wa0 = ra[0], wa1 = ra[1];          // memory_ab row
        vfloat4 wl0 = rl[0], wl1 = rl[1];          // memory_l  row
        const vfloat4* lq = (const vfloat4*)(ws_f + WS_LN  + (size_t)b * FEAT) + lane16 * 2;
        const vfloat4* aq = (const vfloat4*)(ws_f + WS_ABN + (size_t)b * FEAT) + lane16 * 2;
        vfloat4 lv0 = lq[0], lv1 = lq[1];
        vfloat4 av0 = aq[0], av1 = aq[1];
        float dl  = dot4(wa0, lv0) + dot4(wa1, lv1);   // -> P_l
        float dab = dot4(wl0, av0) + dot4(wl1, av1);   // -> P_ab
        #pragma unroll
        for (int m = 1; m < 16; m <<= 1) {
            dl  += __shfl_xor(dl,  m, 64);
            dab += __shfl_xor(dab, m, 64);
        }
        if (lane16 == 0) {
            out[O_OUTL + (size_t)b * KP1 + k] = __expf(dl  * INV_T);
            out[O_OUTA + (size_t)b * KP1 + k] = __expf(dab * INV_T);
        }
    }
}

// ---------------------------------------------------------------------------
// 4a) Z partials from the completed P arrays, fixed slicing (deterministic)
// ---------------------------------------------------------------------------
__global__ void zsum_kernel(const float* __restrict__ out,
                            float* __restrict__ pl, float* __restrict__ pa) {
    __shared__ float sl[256], sa[256];
    int i = blockIdx.x, t = threadIdx.x;
    const float* bl = out + O_OUTL + (size_t)i * KP1;
    const float* ba = out + O_OUTA + (size_t)i * KP1;
    float a = 0.f, b = 0.f;
    for (int p = t; p < KP1; p += 256) { a += bl[p]; b += ba[p]; }
    sl[t] = a; sa[t] = b;
    __syncthreads();
    for (int s = 128; s > 0; s >>= 1) {
        if (t < s) { sl[t] += sl[t + s]; sa[t] += sa[t + s]; }
        __syncthreads();
    }
    if (t == 0) { pl[i] = sl[0]; pa[i] = sa[0]; }
}

// ---------------------------------------------------------------------------
// 4b) final Z -> 1/Z
// ---------------------------------------------------------------------------
__global__ void zfinal_kernel(const float* __restrict__ pl,
                              const float* __restrict__ pa,
                              float* __restrict__ invz) {
    if (threadIdx.x == 0) {
        float a = 0.f, b = 0.f;
        for (int i = 0; i < 256; ++i) { a += pl[i]; b += pa[i]; }
        float count = (float)TOTP;
        invz[0] = count / (a * (float)NBANK);
        invz[1] = count / (b * (float)NBANK);
    }
}

// ---------------------------------------------------------------------------
// 5) Scale both P regions in place by 1/Z
// ---------------------------------------------------------------------------
__global__ void scale_kernel(float* __restrict__ out, const float* __restrict__ invz) {
    float zl = invz[0], za = invz[1];
    size_t stride = (size_t)gridDim.x * blockDim.x;
    for (size_t i = (size_t)blockIdx.x * blockDim.x + threadIdx.x; i < TOTP; i += stride) {
        out[O_OUTL + i] *= zl;
        out[O_OUTA + i] *= za;
    }
}

// ---------------------------------------------------------------------------
// 6) Momentum scatter update (reads ORIGINAL banks, writes into d_out copies)
//    Last-wins on duplicate y to match numpy scatter semantics.
// ---------------------------------------------------------------------------
__global__ void update_kernel(const float* __restrict__ mem_l,
                              const float* __restrict__ mem_ab,
                              const int*   __restrict__ y,
                              const float* __restrict__ ws,
                              float* __restrict__ out) {
    int b    = blockIdx.x;
    int lane = threadIdx.x;
    int row  = y[b];
    for (int j = b + 1; j < BATCH; ++j)
        if (y[j] == row) return;              // a later write wins
    {
        float2 m = ((const float2*)(mem_l + (size_t)row * FEAT))[lane];
        float2 x = ((const float2*)(ws + WS_LN + (size_t)b * FEAT))[lane];
        float2 p = make_float2(m.x * 0.5f + x.x * 0.5f, m.y * 0.5f + x.y * 0.5f);
        float ss = p.x * p.x + p.y * p.y;
        #pragma unroll
        for (int mk = 1; mk < 64; mk <<= 1) ss += __shfl_xor(ss, mk, 64);
        float nrm = sqrtf(ss);
        ((float2*)(out + O_MEML + (size_t)row * FEAT))[lane] =
            make_float2(p.x / nrm, p.y / nrm);
    }
    {
        float2 m = ((const float2*)(mem_ab + (size_t)row * FEAT))[lane];
        float2 x = ((const float2*)(ws + WS_ABN + (size_t)b * FEAT))[lane];
        float2 p = make_float2(m.x * 0.5f + x.x * 0.5f, m.y * 0.5f + x.y * 0.5f);
        float ss = p.x * p.x + p.y * p.y;
        #pragma unroll
        for (int mk = 1; mk < 64; mk <<= 1) ss += __shfl_xor(ss, mk, 64);
        float nrm = sqrtf(ss);
        ((float2*)(out + O_MEMA + (size_t)row * FEAT))[lane] =
            make_float2(p.x / nrm, p.y / nrm);
    }
}

// ---------------------------------------------------------------------------
extern "C" void kernel_launch(void* const* d_in, const int* in_sizes, int n_in,
                              void* d_out, int out_size, void* d_ws, size_t ws_size,
                              hipStream_t stream) {
    const float* l      = (const float*)d_in[0];
    const float* ab     = (const float*)d_in[1];
    const float* mem_l  = (const float*)d_in[2];
    const float* mem_ab = (const float*)d_in[3];
    const int*   y      = (const int*)d_in[4];
    const int*   idx    = (const int*)d_in[5];
    float* out = (float*)d_out;
    float* ws  = (float*)d_ws;

    unsigned int* wsu = (unsigned int*)(ws + WS_U32);
    unsigned int* cnt = wsu;
    unsigned int* ent = wsu + NBUCK;

    // 1) normalize queries + zero bucket counters
    norm_zero_kernel<<<dim3(2 * BATCH), dim3(64), 0, stream>>>(l, ab, ws, cnt);
    // 2) one-pass inverted index build (fixed-capacity buckets)
    build_kernel<<<dim3(2048), dim3(256), 0, stream>>>(idx, cnt, ent);
    // 3) stream banks: stage -> copy-out (overlapped) -> score from LDS
    main_kernel<<<dim3(NBUCK), dim3(256), 0, stream>>>(
        mem_l, mem_ab, ws, cnt, ent, out);
    // 4) Z from completed P arrays (fixed order)
    zsum_kernel  <<<dim3(256), dim3(256), 0, stream>>>(out, ws + WS_PL, ws + WS_PA);
    zfinal_kernel<<<dim3(1),   dim3(64),  0, stream>>>(ws + WS_PL, ws + WS_PA, ws + WS_INVZ);
    // 5) scale P by 1/Z
    scale_kernel<<<dim3(1024), dim3(256), 0, stream>>>(out, ws + WS_INVZ);
    // 6) momentum scatter update (after copy, last-wins)
    update_kernel<<<dim3(BATCH), dim3(64), 0, stream>>>(mem_l, mem_ab, y, ws, out);
}

// Round 8
// 490.695 us; speedup vs baseline: 1.4982x; 1.0005x over previous
//
#include <hip/hip_runtime.h>
#include <math.h>
#include <stdint.h>

// Problem constants (match reference)
#define FEAT   128
#define NBANK  1000000
#define KP1    4097            // K_NEG + 1
#define BATCH  256
#define INV_T  2.0f            // 1 / T, T = 0.5
#define EPS_N  1e-7f

// Output layout (floats, concatenated in return order)
constexpr size_t TOTP   = (size_t)BATCH * KP1;        // 1048832 per score output
constexpr size_t O_OUTL = 0;
constexpr size_t O_OUTA = TOTP;                       // 1048832
constexpr size_t O_MEML = 2 * TOTP;                   // 2097664
constexpr size_t O_MEMA = O_MEML + (size_t)NBANK * FEAT; // 130097664

// Inverted-index geometry: buckets of 16 bank rows, fixed-capacity slots.
// Avg entries/bucket = 1048832/62500 = 16.8 (Poisson); CAP=128 is ~27 sigma.
constexpr int RPB   = 16;
constexpr int NBUCK = NBANK / RPB;                    // 62500 (exact)
constexpr int CAP   = 128;

// Workspace layout. Float region first, then u32 region.
constexpr size_t WS_LN   = 0;        // 256*128 floats
constexpr size_t WS_ABN  = 32768;    // 256*128 floats
constexpr size_t WS_INVZ = 65536;    // 2 floats
constexpr size_t WS_PL   = 65544;    // 256 floats (Z partials, out_l)
constexpr size_t WS_PA   = 65800;    // 256 floats (Z partials, out_ab)
constexpr size_t WS_U32  = 66560;    // u32 region starts here (float index)
// u32 region: CNT[NBUCK], ENT[NBUCK*CAP]  (~32.3 MB total; ws is ~4 GB)

typedef float vfloat4 __attribute__((ext_vector_type(4)));

__device__ __forceinline__ float dot4(vfloat4 a, vfloat4 b) {
    return a.x * b.x + a.y * b.y + a.z * b.z + a.w * b.w;
}

// ---------------------------------------------------------------------------
// 1) L2-normalize l and ab rows + zero bucket counters (grid-stride, folded).
//    512 blocks x 64 threads.
// ---------------------------------------------------------------------------
__global__ void norm_zero_kernel(const float* __restrict__ l,
                                 const float* __restrict__ ab,
                                 float* __restrict__ ws,
                                 unsigned int* __restrict__ cnt) {
    int b    = blockIdx.x;
    int lane = threadIdx.x;           // 0..63, 2 floats per lane
    for (int i = b * 64 + lane; i < NBUCK; i += 512 * 64) cnt[i] = 0u;
    const float* src;
    float*       dst;
    if (b < BATCH) { src = l  + (size_t)b * FEAT;            dst = ws + WS_LN  + (size_t)b * FEAT; }
    else           { src = ab + (size_t)(b - BATCH) * FEAT;  dst = ws + WS_ABN + (size_t)(b - BATCH) * FEAT; }
    float2 v = *(const float2*)(src + 2 * lane);
    float  ss = v.x * v.x + v.y * v.y;
    #pragma unroll
    for (int m = 1; m < 64; m <<= 1) ss += __shfl_xor(ss, m, 64);
    float inv = 1.0f / (sqrtf(ss) + EPS_N);
    ((float2*)dst)[lane] = make_float2(v.x * inv, v.y * inv);
}

// ---------------------------------------------------------------------------
// 2) Build inverted index in ONE pass: fixed-capacity buckets.
//    Entry pack: (b<<17)|(k<<4)|(row&15). Order within bucket is arbitrary
//    (atomic), but every (b,k) gets exactly one slot -> P deterministic.
// ---------------------------------------------------------------------------
__global__ void build_kernel(const int* __restrict__ idx,
                             unsigned int* __restrict__ cnt,
                             unsigned int* __restrict__ ent) {
    size_t stride = (size_t)gridDim.x * blockDim.x;
    for (size_t p = (size_t)blockIdx.x * blockDim.x + threadIdx.x; p < TOTP; p += stride) {
        int row = idx[p];
        int b   = (int)(p / KP1);
        int k   = (int)(p - (size_t)b * KP1);
        int bucket = row >> 4;
        unsigned int pos = atomicAdd(&cnt[bucket], 1u);
        if (pos < (unsigned int)CAP)
            ent[(size_t)bucket * CAP + pos] =
                ((unsigned int)b << 17) | ((unsigned int)k << 4) | (unsigned int)(row & 15);
    }
}

// ---------------------------------------------------------------------------
// 3) MAIN: stream a 16-row window of both banks. Per block:
//    entry loads first (latency overlapped) -> bank loads (regs) -> LDS
//    writes -> barrier -> plain stores (copy-out, overlap w/ score) -> score.
//    LDS ~16.5 KB -> 8 blocks/CU (100% thread occupancy): enough independent
//    blocks that some are always issuing loads while others drain.
// ---------------------------------------------------------------------------
__global__ __launch_bounds__(256) void main_kernel(
        const float* __restrict__ mem_l, const float* __restrict__ mem_ab,
        const float* __restrict__ ws_f,            // ln/abn tables
        const unsigned int* __restrict__ cnt,
        const unsigned int* __restrict__ ent,
        float* __restrict__ out) {
    __shared__ float ldsL[RPB * FEAT];   // 8 KB
    __shared__ float ldsA[RPB * FEAT];   // 8 KB
    __shared__ unsigned int sEnt[CAP];   // 512 B
    int blk = blockIdx.x;                // 0..NBUCK-1
    int tid = threadIdx.x;
    size_t fbase = (size_t)blk * RPB * FEAT;       // float offset of window

    // ---- entry staging first: its latency hides under the bank loads ----
    int c = min((int)cnt[blk], CAP);
    if (tid < CAP && tid < c) sEnt[tid] = ent[(size_t)blk * CAP + tid];

    // ---- bank loads: 2 float4 per thread per bank (8 KB each) ----
    const vfloat4* sl = (const vfloat4*)(mem_l  + fbase);
    const vfloat4* sa = (const vfloat4*)(mem_ab + fbase);
    vfloat4 vl[2], va[2];
    #pragma unroll
    for (int j = 0; j < 2; ++j) vl[j] = sl[j * 256 + tid];
    #pragma unroll
    for (int j = 0; j < 2; ++j) va[j] = sa[j * 256 + tid];

    // ---- LDS writes ----
    vfloat4* lL = (vfloat4*)ldsL;
    vfloat4* lA = (vfloat4*)ldsA;
    #pragma unroll
    for (int j = 0; j < 2; ++j) { int i = j * 256 + tid; lL[i] = vl[j]; lA[i] = va[j]; }
    __syncthreads();

    // ---- copy-out (plain stores, overlap with score below) ----
    vfloat4* dl_ = (vfloat4*)(out + O_MEML + fbase);
    vfloat4* da_ = (vfloat4*)(out + O_MEMA + fbase);
    #pragma unroll
    for (int j = 0; j < 2; ++j) { int i = j * 256 + tid; dl_[i] = vl[j]; da_[i] = va[j]; }

    // ---- score this window's entries from LDS ----
    int g = tid >> 4, lane16 = tid & 15;           // 16 groups of 16 lanes
    for (int i = g; i < c; i += 16) {
        unsigned int ev = sEnt[i];
        int rloc = (int)(ev & 15u);
        int k    = (int)((ev >> 4) & 0x1FFFu);
        int b    = (int)(ev >> 17);
        const vfloat4* ra = (const vfloat4*)(ldsA + rloc * FEAT) + lane16 * 2;
        const vfloat4* rl = (const vfloat4*)(ldsL + rloc * FEAT) + lane16 * 2;
        vfloat4 wa0 = ra[0], wa1 = ra[1];          // memory_ab row
        vfloat4 wl0 = rl[0], wl1 = rl[1];          // memory_l  row
        const vfloat4* lq = (const vfloat4*)(ws_f + WS_LN  + (size_t)b * FEAT) + lane16 * 2;
        const vfloat4* aq = (const vfloat4*)(ws_f + WS_ABN + (size_t)b * FEAT) + lane16 * 2;
        vfloat4 lv0 = lq[0], lv1 = lq[1];
        vfloat4 av0 = aq[0], av1 = aq[1];
        float dl  = dot4(wa0, lv0) + dot4(wa1, lv1);   // -> P_l
        float dab = dot4(wl0, av0) + dot4(wl1, av1);   // -> P_ab
        #pragma unroll
        for (int m = 1; m < 16; m <<= 1) {
            dl  += __shfl_xor(dl,  m, 64);
            dab += __shfl_xor(dab, m, 64);
        }
        if (lane16 == 0) {
            out[O_OUTL + (size_t)b * KP1 + k] = __expf(dl  * INV_T);
            out[O_OUTA + (size_t)b * KP1 + k] = __expf(dab * INV_T);
        }
    }
}

// ---------------------------------------------------------------------------
// 4a) Z partials from the completed P arrays, fixed slicing (deterministic)
// ---------------------------------------------------------------------------
__global__ void zsum_kernel(const float* __restrict__ out,
                            float* __restrict__ pl, float* __restrict__ pa) {
    __shared__ float sl[256], sa[256];
    int i = blockIdx.x, t = threadIdx.x;
    const float* bl = out + O_OUTL + (size_t)i * KP1;
    const float* ba = out + O_OUTA + (size_t)i * KP1;
    float a = 0.f, b = 0.f;
    for (int p = t; p < KP1; p += 256) { a += bl[p]; b += ba[p]; }
    sl[t] = a; sa[t] = b;
    __syncthreads();
    for (int s = 128; s > 0; s >>= 1) {
        if (t < s) { sl[t] += sl[t + s]; sa[t] += sa[t + s]; }
        __syncthreads();
    }
    if (t == 0) { pl[i] = sl[0]; pa[i] = sa[0]; }
}

// ---------------------------------------------------------------------------
// 4b) final Z -> 1/Z
// ---------------------------------------------------------------------------
__global__ void zfinal_kernel(const float* __restrict__ pl,
                              const float* __restrict__ pa,
                              float* __restrict__ invz) {
    if (threadIdx.x == 0) {
        float a = 0.f, b = 0.f;
        for (int i = 0; i < 256; ++i) { a += pl[i]; b += pa[i]; }
        float count = (float)TOTP;
        invz[0] = count / (a * (float)NBANK);
        invz[1] = count / (b * (float)NBANK);
    }
}

// ---------------------------------------------------------------------------
// 5) Scale both P regions in place by 1/Z
// ---------------------------------------------------------------------------
__global__ void scale_kernel(float* __restrict__ out, const float* __restrict__ invz) {
    float zl = invz[0], za = invz[1];
    size_t stride = (size_t)gridDim.x * blockDim.x;
    for (size_t i = (size_t)blockIdx.x * blockDim.x + threadIdx.x; i < TOTP; i += stride) {
        out[O_OUTL + i] *= zl;
        out[O_OUTA + i] *= za;
    }
}

// ---------------------------------------------------------------------------
// 6) Momentum scatter update (reads ORIGINAL banks, writes into d_out copies)
//    Last-wins on duplicate y to match numpy scatter semantics.
// ---------------------------------------------------------------------------
__global__ void update_kernel(const float* __restrict__ mem_l,
                              const float* __restrict__ mem_ab,
                              const int*   __restrict__ y,
                              const float* __restrict__ ws,
                              float* __restrict__ out) {
    int b    = blockIdx.x;
    int lane = threadIdx.x;
    int row  = y[b];
    for (int j = b + 1; j < BATCH; ++j)
        if (y[j] == row) return;              // a later write wins
    {
        float2 m = ((const float2*)(mem_l + (size_t)row * FEAT))[lane];
        float2 x = ((const float2*)(ws + WS_LN + (size_t)b * FEAT))[lane];
        float2 p = make_float2(m.x * 0.5f + x.x * 0.5f, m.y * 0.5f + x.y * 0.5f);
        float ss = p.x * p.x + p.y * p.y;
        #pragma unroll
        for (int mk = 1; mk < 64; mk <<= 1) ss += __shfl_xor(ss, mk, 64);
        float nrm = sqrtf(ss);
        ((float2*)(out + O_MEML + (size_t)row * FEAT))[lane] =
            make_float2(p.x / nrm, p.y / nrm);
    }
    {
        float2 m = ((const float2*)(mem_ab + (size_t)row * FEAT))[lane];
        float2 x = ((const float2*)(ws + WS_ABN + (size_t)b * FEAT))[lane];
        float2 p = make_float2(m.x * 0.5f + x.x * 0.5f, m.y * 0.5f + x.y * 0.5f);
        float ss = p.x * p.x + p.y * p.y;
        #pragma unroll
        for (int mk = 1; mk < 64; mk <<= 1) ss += __shfl_xor(ss, mk, 64);
        float nrm = sqrtf(ss);
        ((float2*)(out + O_MEMA + (size_t)row * FEAT))[lane] =
            make_float2(p.x / nrm, p.y / nrm);
    }
}

// ---------------------------------------------------------------------------
extern "C" void kernel_launch(void* const* d_in, const int* in_sizes, int n_in,
                              void* d_out, int out_size, void* d_ws, size_t ws_size,
                              hipStream_t stream) {
    const float* l      = (const float*)d_in[0];
    const float* ab     = (const float*)d_in[1];
    const float* mem_l  = (const float*)d_in[2];
    const float* mem_ab = (const float*)d_in[3];
    const int*   y      = (const int*)d_in[4];
    const int*   idx    = (const int*)d_in[5];
    float* out = (float*)d_out;
    float* ws  = (float*)d_ws;

    unsigned int* wsu = (unsigned int*)(ws + WS_U32);
    unsigned int* cnt = wsu;
    unsigned int* ent = wsu + NBUCK;

    // 1) normalize queries + zero bucket counters
    norm_zero_kernel<<<dim3(2 * BATCH), dim3(64), 0, stream>>>(l, ab, ws, cnt);
    // 2) one-pass inverted index build (fixed-capacity buckets)
    build_kernel<<<dim3(2048), dim3(256), 0, stream>>>(idx, cnt, ent);
    // 3) stream banks: stage -> copy-out (overlapped) -> score from LDS
    main_kernel<<<dim3(NBUCK), dim3(256), 0, stream>>>(
        mem_l, mem_ab, ws, cnt, ent, out);
    // 4) Z from completed P arrays (fixed order)
    zsum_kernel  <<<dim3(256), dim3(256), 0, stream>>>(out, ws + WS_PL, ws + WS_PA);
    zfinal_kernel<<<dim3(1),   dim3(64),  0, stream>>>(ws + WS_PL, ws + WS_PA, ws + WS_INVZ);
    // 5) scale P by 1/Z
    scale_kernel<<<dim3(1024), dim3(256), 0, stream>>>(out, ws + WS_INVZ);
    // 6) momentum scatter update (after copy, last-wins)
    update_kernel<<<dim3(BATCH), dim3(64), 0, stream>>>(mem_l, mem_ab, y, ws, out);
}